// Round 4
// baseline (145.076 us; speedup 1.0000x reference)
//
#include <hip/hip_runtime.h>

// Backflow: out[b] = sum_d det(g[b,d]) * bf[d]
//   g[b,d][i][j] = sum_h h2[b,h]*Wg[h,d,sel[b,i],j] + bg[d,sel[b,i],j]
// B=8192, O=64, E=16, D=16, H=4.
//
// One wave per sample; 4 lanes per det (lane l owns rows l, l+4, l+8, l+12 =
// arrays R0..R3). No-pivot LU in a SMALL ROLLED loop:
//  - quad broadcast from runtime lane kk via masked-sum DPP (static ctrls)
//  - column-shift trick: R[j-1] = fma(-f, pv, R[j]) keeps pivot col at [0]
//  - slot rotation folded into the 4th step of each round (rotated writes)
// Zero LDS-pipe ops and zero ballots in the hot loop; ~2.5 KB loop body.
// Dets with |pivot| < 1e-3*mat_max are recomputed with a rolled pivoted
// fallback (cold path).

template <int CTRL>
__device__ __forceinline__ float dpp_movf(float v) {
    return __int_as_float(__builtin_amdgcn_update_dpp(
        0, __float_as_int(v), CTRL, 0xF, 0xF, true));
}

// broadcast x from the quad lane where own==true (static DPP ctrls)
__device__ __forceinline__ float qbcast(float x, bool own) {
    float t = own ? x : 0.0f;
    t += dpp_movf<0xB1>(t);   // quad_perm [1,0,3,2]
    t += dpp_movf<0x4E>(t);   // quad_perm [2,3,0,1]
    return t;
}

__global__ __launch_bounds__(128) void backflow_kernel(
    const float* __restrict__ x,    // (B,64)
    const float* __restrict__ W1,   // (64,4)
    const float* __restrict__ b1,   // (4,)
    const float* __restrict__ W2,   // (4,4)
    const float* __restrict__ b2,   // (4,)
    const float* __restrict__ Wg,   // (4,16,64,16)
    const float* __restrict__ bg,   // (16,64,16)
    const float* __restrict__ bf,   // (16,1)
    float* __restrict__ out,        // (B,)
    int B)
{
    const int lane  = threadIdx.x & 63;
    const int wavei = threadIdx.x >> 6;
    const int b     = blockIdx.x * 2 + wavei;
    if (b >= B) return;
    const int d  = lane >> 2;   // det index 0..15
    const int l  = lane & 3;    // lane-in-quad
    const int qb = lane & ~3;

    // ---- occupied-orbital mask ----
    const float xv = x[b * 64 + lane];
    const unsigned long long mask = __ballot(xv != 0.0f);
    const bool empty = ((mask & ~1ull) == 0ull);

    // ---- h1 = relu(x @ W1 + b1): 64-lane butterfly ----
    const float4 w1 = reinterpret_cast<const float4*>(W1)[lane];
    float c0 = xv * w1.x, c1 = xv * w1.y, c2 = xv * w1.z, c3 = xv * w1.w;
    #pragma unroll
    for (int off = 32; off >= 1; off >>= 1) {
        c0 += __shfl_xor(c0, off);
        c1 += __shfl_xor(c1, off);
        c2 += __shfl_xor(c2, off);
        c3 += __shfl_xor(c3, off);
    }
    const float h10 = fmaxf(c0 + b1[0], 0.0f);
    const float h11 = fmaxf(c1 + b1[1], 0.0f);
    const float h12 = fmaxf(c2 + b1[2], 0.0f);
    const float h13 = fmaxf(c3 + b1[3], 0.0f);

    // ---- h2 = relu(h1 @ W2 + b2) ----
    float h2[4];
    #pragma unroll
    for (int j = 0; j < 4; ++j) {
        float v = b2[j];
        v = fmaf(h10, W2[0 * 4 + j], v);
        v = fmaf(h11, W2[1 * 4 + j], v);
        v = fmaf(h12, W2[2 * 4 + j], v);
        v = fmaf(h13, W2[3 * 4 + j], v);
        h2[j] = fmaxf(v, 0.0f);
    }

    // ---- sel for owned rows l, l+4, l+8, l+12 ----
    unsigned long long m = mask;
    if (l & 1) { m &= m - 1; }
    if (l & 2) { m &= m - 1; m &= m - 1; }
    const int s0 = m ? (int)__builtin_ctzll(m) : 0;
    m &= m-1; m &= m-1; m &= m-1; m &= m-1;
    const int s1 = m ? (int)__builtin_ctzll(m) : 0;
    m &= m-1; m &= m-1; m &= m-1; m &= m-1;
    const int s2 = m ? (int)__builtin_ctzll(m) : 0;
    m &= m-1; m &= m-1; m &= m-1; m &= m-1;
    const int s3 = m ? (int)__builtin_ctzll(m) : 0;

    float R0[16], R1[16], R2[16], R3[16];

#define BUILD_ROW(RW, SQ) do {                                                   \
    const float* base = Wg + ((size_t)d * 64 + (SQ)) * 16;                       \
    const float4* p0 = reinterpret_cast<const float4*>(base);                    \
    const float4* p1 = reinterpret_cast<const float4*>(base + 16384);            \
    const float4* p2 = reinterpret_cast<const float4*>(base + 32768);            \
    const float4* p3 = reinterpret_cast<const float4*>(base + 49152);            \
    const float4* pb = reinterpret_cast<const float4*>(bg + ((size_t)d * 64 + (SQ)) * 16); \
    _Pragma("unroll")                                                            \
    for (int q = 0; q < 4; ++q) {                                                \
        const float4 a0 = p0[q], a1 = p1[q], a2 = p2[q], a3 = p3[q], ab = pb[q]; \
        RW[q*4+0] = fmaf(h2[0],a0.x, fmaf(h2[1],a1.x, fmaf(h2[2],a2.x, fmaf(h2[3],a3.x, ab.x)))); \
        RW[q*4+1] = fmaf(h2[0],a0.y, fmaf(h2[1],a1.y, fmaf(h2[2],a2.y, fmaf(h2[3],a3.y, ab.y)))); \
        RW[q*4+2] = fmaf(h2[0],a0.z, fmaf(h2[1],a1.z, fmaf(h2[2],a2.z, fmaf(h2[3],a3.z, ab.z)))); \
        RW[q*4+3] = fmaf(h2[0],a0.w, fmaf(h2[1],a1.w, fmaf(h2[2],a2.w, fmaf(h2[3],a3.w, ab.w)))); \
    } } while (0)

    BUILD_ROW(R0, s0);
    BUILD_ROW(R1, s1);
    BUILD_ROW(R2, s2);
    BUILD_ROW(R3, s3);

    // ---- matrix scale for pivot-quality flag (quad-uniform) ----
    float mm = 0.0f;
    #pragma unroll
    for (int j = 0; j < 16; ++j) {
        mm = fmaxf(mm, fmaxf(fmaxf(fabsf(R0[j]), fabsf(R1[j])),
                             fmaxf(fabsf(R2[j]), fabsf(R3[j]))));
    }
    mm = fmaxf(mm, dpp_movf<0xB1>(mm));
    mm = fmaxf(mm, dpp_movf<0x4E>(mm));
    const float tau = 1e-3f * mm;

    // ---- no-pivot LU, rolled; rounds of 4 steps; rotation folded in step 4 ----
    double det  = 1.0;
    float  sign = 1.0f;
    bool   bad  = false;

    #pragma unroll 1
    for (int g = 0; g < 4; ++g) {
        const bool a1v = (g <= 2), a2v = (g <= 1), a3v = (g == 0);
        #pragma unroll 1
        for (int kk = 0; kk < 3; ++kk) {
            const bool oc = (l == kk);
            const float pivot = qbcast(R0[0], oc);
            bad = bad || !(fabsf(pivot) >= tau);
            det *= (double)pivot;
            float pinv = __builtin_amdgcn_rcpf(pivot);
            pinv = pinv * (2.0f - pivot * pinv);
            const float f0 = (l > kk) ? R0[0] * pinv : 0.0f;
            const float f1 = a1v ? R1[0] * pinv : 0.0f;
            const float f2 = a2v ? R2[0] * pinv : 0.0f;
            const float f3 = a3v ? R3[0] * pinv : 0.0f;
            #pragma unroll
            for (int j = 1; j < 16; ++j) {
                const float pv = qbcast(R0[j], oc);
                R0[j-1] = fmaf(-f0, pv, R0[j]);
                R1[j-1] = fmaf(-f1, pv, R1[j]);
                R2[j-1] = fmaf(-f2, pv, R2[j]);
                R3[j-1] = fmaf(-f3, pv, R3[j]);
            }
        }
        {   // kk == 3: rotated writes retire R0, shift slots down
            const bool oc = (l == 3);
            const float pivot = qbcast(R0[0], oc);
            bad = bad || !(fabsf(pivot) >= tau);
            det *= (double)pivot;
            float pinv = __builtin_amdgcn_rcpf(pivot);
            pinv = pinv * (2.0f - pivot * pinv);
            const float f1 = a1v ? R1[0] * pinv : 0.0f;
            const float f2 = a2v ? R2[0] * pinv : 0.0f;
            const float f3 = a3v ? R3[0] * pinv : 0.0f;
            #pragma unroll
            for (int j = 1; j < 16; ++j) {
                const float pv = qbcast(R0[j], oc);
                const float n0 = fmaf(-f1, pv, R1[j]);
                const float n1 = fmaf(-f2, pv, R2[j]);
                const float n2 = fmaf(-f3, pv, R3[j]);
                R0[j-1] = n0; R1[j-1] = n1; R2[j-1] = n2;
            }
        }
    }

    // ---- cold fallback: rolled partial-pivoting recompute for flagged quads ----
    if (bad) {
        BUILD_ROW(R0, s0);
        BUILD_ROW(R1, s1);
        BUILD_ROW(R2, s2);
        BUILD_ROW(R3, s3);
        det  = 1.0;
        sign = 1.0f;
        int vr0 = l, vr1 = 4 + l, vr2 = 8 + l, vr3 = 12 + l;
        #pragma unroll 1
        for (int k = 0; k < 16; ++k) {
            const float c0a = (vr0 >= k) ? fabsf(R0[0]) : -1.0f;
            const float c1a = (vr1 >= k) ? fabsf(R1[0]) : -1.0f;
            const float c2a = (vr2 >= k) ? fabsf(R2[0]) : -1.0f;
            const float c3a = (vr3 >= k) ? fabsf(R3[0]) : -1.0f;
            const float mx01 = fmaxf(c0a, c1a);
            const float mx23 = fmaxf(c2a, c3a);
            const float lmx  = fmaxf(mx01, mx23);
            int lslot = (c0a >= c1a) ? 0 : 1;
            lslot = (mx01 >= mx23) ? lslot : ((c2a >= c3a) ? 2 : 3);
            float qmx = fmaxf(lmx, dpp_movf<0xB1>(lmx));
            qmx = fmaxf(qmx, dpp_movf<0x4E>(qmx));
            const unsigned long long bal = __ballot(lmx == qmx);
            const int p = qb + (int)__builtin_ctzll((bal >> qb) & 0xFull);

            const bool own = (lane == p);
            const bool pm0 = own && (lslot == 0);
            const bool pm1 = own && (lslot == 1);
            const bool pm2 = own && (lslot == 2);
            const bool pm3 = own && (lslot == 3);

            const int vloc = pm0 ? vr0 : pm1 ? vr1 : pm2 ? vr2 : vr3;
            const int vp   = __shfl(vloc, p);
            sign = (vp != k) ? -sign : sign;

            const float pl    = pm0 ? R0[0] : pm1 ? R1[0] : pm2 ? R2[0] : R3[0];
            const float pivot = __shfl(pl, p);
            det *= (double)pivot;
            const float pinv = (pivot != 0.0f) ? __builtin_amdgcn_rcpf(pivot) : 0.0f;

            vr0 = pm0 ? k : (vr0 == k ? vp : vr0);
            vr1 = pm1 ? k : (vr1 == k ? vp : vr1);
            vr2 = pm2 ? k : (vr2 == k ? vp : vr2);
            vr3 = pm3 ? k : (vr3 == k ? vp : vr3);

            const float f0 = (vr0 > k) ? R0[0] * pinv : 0.0f;
            const float f1 = (vr1 > k) ? R1[0] * pinv : 0.0f;
            const float f2 = (vr2 > k) ? R2[0] * pinv : 0.0f;
            const float f3 = (vr3 > k) ? R3[0] * pinv : 0.0f;

            #pragma unroll
            for (int j = 1; j < 16; ++j) {
                const float vj = pm0 ? R0[j] : pm1 ? R1[j] : pm2 ? R2[j] : R3[j];
                const float pv = __shfl(vj, p);
                R0[j-1] = fmaf(-f0, pv, R0[j]);
                R1[j-1] = fmaf(-f1, pv, R1[j]);
                R2[j-1] = fmaf(-f2, pv, R2[j]);
                R3[j-1] = fmaf(-f3, pv, R3[j]);
            }
        }
    }
#undef BUILD_ROW

    // ---- combine: det_d (uniform in quad) dotted with bf ----
    const float detf = sign * (float)det;
    float acc = (l == 0) ? detf * bf[d] : 0.0f;
    acc += __shfl_xor(acc, 4);
    acc += __shfl_xor(acc, 8);
    acc += __shfl_xor(acc, 16);
    acc += __shfl_xor(acc, 32);
    if (lane == 0) out[b] = empty ? 0.0f : acc;
}

extern "C" void kernel_launch(void* const* d_in, const int* in_sizes, int n_in,
                              void* d_out, int out_size, void* d_ws, size_t ws_size,
                              hipStream_t stream) {
    const float* x  = (const float*)d_in[0];
    const float* W1 = (const float*)d_in[1];
    const float* b1 = (const float*)d_in[2];
    const float* W2 = (const float*)d_in[3];
    const float* b2 = (const float*)d_in[4];
    const float* Wg = (const float*)d_in[5];
    const float* bg = (const float*)d_in[6];
    const float* bf = (const float*)d_in[7];
    float* out = (float*)d_out;

    const int B = in_sizes[0] / 64;
    const int blocks = (B + 1) / 2;   // 2 samples (waves) per 128-thread block
    backflow_kernel<<<blocks, 128, 0, stream>>>(x, W1, b1, W2, b2, Wg, bg, bf, out, B);
}

// Round 5
// 135.880 us; speedup vs baseline: 1.0677x; 1.0677x over previous
//
#include <hip/hip_runtime.h>

// Backflow: out[b] = sum_d det(g[b,d]) * bf[d]
//   g[b,d][i][j] = sum_h h2[b,h]*Wg[h,d,sel[b,i],j] + bg[d,sel[b,i],j]
// B=8192, O=64, E=16, D=16, H=4.
//
// Block = 1 sample (4 waves). Wave t handles dets d = grp*4 + t via its four
// 16-lane groups (row r per lane) -> 32768 waves total (4x oversubscription of
// the 8192 wave slots), and each wave runs ONE 16-step LU chain instead of
// R1's four sequential ones. Pivot max-reduce uses DPP row_ror rotate-reduce
// (VALU, ~8cy/stage) instead of 4 serial ds_swizzles (~40cy each); only the
// two pivot broadcasts per k-step touch the LDS pipe.

template <int CTRL>
__device__ __forceinline__ float dpp_movf(float v) {
    return __int_as_float(__builtin_amdgcn_update_dpp(
        0, __float_as_int(v), CTRL, 0xF, 0xF, true));
}

__global__ __launch_bounds__(256) void backflow_kernel(
    const float* __restrict__ x,    // (B,64)
    const float* __restrict__ W1,   // (64,4)
    const float* __restrict__ b1,   // (4,)
    const float* __restrict__ W2,   // (4,4)
    const float* __restrict__ b2,   // (4,)
    const float* __restrict__ Wg,   // (4,16,64,16)
    const float* __restrict__ bg,   // (16,64,16)
    const float* __restrict__ bf,   // (16,1)
    float* __restrict__ out,        // (B,)
    int B)
{
    const int lane = threadIdx.x & 63;
    const int t    = threadIdx.x >> 6;   // wave index in block = t-group 0..3
    const int b    = blockIdx.x;
    const int r    = lane & 15;          // row within det group
    const int grp  = lane >> 4;          // det group 0..3 within wave
    const int d    = grp * 4 + t;        // det index 0..15

    __shared__ float part[4];

    // ---- occupied-orbital mask + per-row selected index ----
    const float xv = x[b * 64 + lane];
    const unsigned long long mask = __ballot(xv != 0.0f);
    unsigned long long m = mask;
    for (int i = 0; i < r; ++i) m &= (m - 1ull);           // clear r lowest set bits
    const int  sel_r = m ? (int)__builtin_ctzll(m) : 0;    // r-th set bit (fill 0)
    const bool empty = ((mask & ~1ull) == 0ull);           // sum(sel)==0 case

    // ---- h1 = relu(x @ W1 + b1): 64-lane butterfly ----
    const float4 w1 = reinterpret_cast<const float4*>(W1)[lane];
    float c0 = xv * w1.x, c1 = xv * w1.y, c2 = xv * w1.z, c3 = xv * w1.w;
    #pragma unroll
    for (int off = 32; off >= 1; off >>= 1) {
        c0 += __shfl_xor(c0, off);
        c1 += __shfl_xor(c1, off);
        c2 += __shfl_xor(c2, off);
        c3 += __shfl_xor(c3, off);
    }
    const float h10 = fmaxf(c0 + b1[0], 0.0f);
    const float h11 = fmaxf(c1 + b1[1], 0.0f);
    const float h12 = fmaxf(c2 + b1[2], 0.0f);
    const float h13 = fmaxf(c3 + b1[3], 0.0f);

    // ---- h2 = relu(h1 @ W2 + b2) ----
    float h2[4];
    #pragma unroll
    for (int j = 0; j < 4; ++j) {
        float v = b2[j];
        v = fmaf(h10, W2[0 * 4 + j], v);
        v = fmaf(h11, W2[1 * 4 + j], v);
        v = fmaf(h12, W2[2 * 4 + j], v);
        v = fmaf(h13, W2[3 * 4 + j], v);
        h2[j] = fmaxf(v, 0.0f);
    }

    // ---- build row r of g[b,d] ----
    const float4* wp0 = reinterpret_cast<const float4*>(Wg + (size_t)((0 * 16 + d) * 64 + sel_r) * 16);
    const float4* wp1 = reinterpret_cast<const float4*>(Wg + (size_t)((1 * 16 + d) * 64 + sel_r) * 16);
    const float4* wp2 = reinterpret_cast<const float4*>(Wg + (size_t)((2 * 16 + d) * 64 + sel_r) * 16);
    const float4* wp3 = reinterpret_cast<const float4*>(Wg + (size_t)((3 * 16 + d) * 64 + sel_r) * 16);
    const float4* bgp = reinterpret_cast<const float4*>(bg + (size_t)(d * 64 + sel_r) * 16);

    float row[16];
    #pragma unroll
    for (int q = 0; q < 4; ++q) {
        const float4 a0 = wp0[q], a1 = wp1[q], a2 = wp2[q], a3 = wp3[q], ab = bgp[q];
        row[q * 4 + 0] = fmaf(h2[0], a0.x, fmaf(h2[1], a1.x, fmaf(h2[2], a2.x, fmaf(h2[3], a3.x, ab.x))));
        row[q * 4 + 1] = fmaf(h2[0], a0.y, fmaf(h2[1], a1.y, fmaf(h2[2], a2.y, fmaf(h2[3], a3.y, ab.y))));
        row[q * 4 + 2] = fmaf(h2[0], a0.z, fmaf(h2[1], a1.z, fmaf(h2[2], a2.z, fmaf(h2[3], a3.z, ab.z))));
        row[q * 4 + 3] = fmaf(h2[0], a0.w, fmaf(h2[1], a1.w, fmaf(h2[2], a2.w, fmaf(h2[3], a3.w, ab.w))));
    }

    // ---- LU with partial pivoting, row-per-lane over 16-lane group ----
    double det  = 1.0;
    float  sign = 1.0f;
    int    vrow = r;      // virtual position of this lane's row
    #pragma unroll
    for (int k = 0; k < 16; ++k) {
        const bool  active = (vrow >= k);
        const float av = active ? fabsf(row[k]) : -1.0f;
        // 16-lane max all-reduce via DPP row_ror (VALU pipe, no LDS)
        float mv = av;
        mv = fmaxf(mv, dpp_movf<0x121>(mv));   // row_ror:1
        mv = fmaxf(mv, dpp_movf<0x122>(mv));   // row_ror:2
        mv = fmaxf(mv, dpp_movf<0x124>(mv));   // row_ror:4
        mv = fmaxf(mv, dpp_movf<0x128>(mv));   // row_ror:8
        const unsigned long long bal = __ballot(active && (av == mv));
        const int p = (grp << 4) + (int)__builtin_ctzll((bal >> (grp << 4)) & 0xFFFFull);

        const float pivot = __shfl(row[k], p);
        const int   vp    = __shfl(vrow, p);
        sign = (vp != k) ? -sign : sign;
        if (lane == p)         vrow = k;
        else if (vrow == k)    vrow = vp;

        det *= (double)pivot;

        const float pinv = (pivot != 0.0f) ? __builtin_amdgcn_rcpf(pivot) : 0.0f;
        const float f    = (vrow > k) ? row[k] * pinv : 0.0f;
        #pragma unroll
        for (int j = k + 1; j < 16; ++j) {
            const float pv = __shfl(row[j], p);
            row[j] = fmaf(-f, pv, row[j]);
        }
    }

    // ---- combine: this wave's 4 dets -> block partial via LDS ----
    const float detf = sign * (float)det;
    float acc = (r == 0) ? detf * bf[d] : 0.0f;
    acc += __shfl_xor(acc, 16);
    acc += __shfl_xor(acc, 32);
    if (lane == 0) part[t] = acc;
    __syncthreads();
    if (threadIdx.x == 0)
        out[b] = empty ? 0.0f : (part[0] + part[1] + part[2] + part[3]);
}

extern "C" void kernel_launch(void* const* d_in, const int* in_sizes, int n_in,
                              void* d_out, int out_size, void* d_ws, size_t ws_size,
                              hipStream_t stream) {
    const float* x  = (const float*)d_in[0];
    const float* W1 = (const float*)d_in[1];
    const float* b1 = (const float*)d_in[2];
    const float* W2 = (const float*)d_in[3];
    const float* b2 = (const float*)d_in[4];
    const float* Wg = (const float*)d_in[5];
    const float* bg = (const float*)d_in[6];
    const float* bf = (const float*)d_in[7];
    float* out = (float*)d_out;

    const int B = in_sizes[0] / 64;
    backflow_kernel<<<B, 256, 0, stream>>>(x, W1, b1, W2, b2, Wg, bg, bf, out, B);
}